// Round 4
// baseline (814.437 us; speedup 1.0000x reference)
//
#include <hip/hip_runtime.h>
#include <hip/hip_bf16.h>

#define NROIS 333
#define BATCH 512
#define NREG 300
#define NCLS 180
#define EPSV 1e-5f
#define SLOPEV 0.3f

typedef __attribute__((ext_vector_type(8))) short bf16x8;
typedef __attribute__((ext_vector_type(4))) float f32x4;

static __device__ __forceinline__ bf16x8 cvt8(const float* p) {
  float4 a0 = *(const float4*)p;
  float4 a1 = *(const float4*)(p + 4);
  union { bf16x8 v; __hip_bfloat16 h[8]; } u;
  u.h[0] = __float2bfloat16(a0.x); u.h[1] = __float2bfloat16(a0.y);
  u.h[2] = __float2bfloat16(a0.z); u.h[3] = __float2bfloat16(a0.w);
  u.h[4] = __float2bfloat16(a1.x); u.h[5] = __float2bfloat16(a1.y);
  u.h[6] = __float2bfloat16(a1.z); u.h[7] = __float2bfloat16(a1.w);
  return u.v;
}

// ---------------- metadata: {in_off, size, out_off, reduced} via binary search ----------------
__global__ void meta_kernel(const int* __restrict__ idx, const int* __restrict__ src,
                            int* __restrict__ meta, int max_in, int max_out,
                            int total, int concat_dim) {
  int r = blockIdx.x * blockDim.x + threadIdx.x;
  if (r >= NROIS) return;
  const int* row = idx + (long)r * max_in;
  int in_off = row[0];
  int lo = 0, hi = max_in;                      // first k with row[k] == total
  while (lo < hi) { int mid = (lo + hi) >> 1; if (row[mid] < total) lo = mid + 1; else hi = mid; }
  int size = lo;
  int t1 = r * max_out;
  lo = 0; hi = concat_dim;
  while (lo < hi) { int mid = (lo + hi) >> 1; if (src[mid] < t1) lo = mid + 1; else hi = mid; }
  int out_off = lo;
  int t2 = t1 + max_out;
  hi = concat_dim;
  while (lo < hi) { int mid = (lo + hi) >> 1; if (src[mid] < t2) lo = mid + 1; else hi = mid; }
  meta[r] = in_off;
  meta[NROIS + r] = size;
  meta[2 * NROIS + r] = out_off;
  meta[3 * NROIS + r] = lo - out_off;
}

// ---------------- seed reg_out with b_reg (d_out poisoned 0xAA; atomics accumulate on top) ----------------
__global__ void init_reg_kernel(const float* __restrict__ b_reg, float* __restrict__ reg_out) {
  int i = blockIdx.x * blockDim.x + threadIdx.x;
  if (i < BATCH * NREG) reg_out[i] = b_reg[i % NREG];
}

// ---------------- encoder: barrier-free direct-fragment MFMA + BN + leaky ----------------
__global__ __launch_bounds__(256) void enc_kernel(
    const float* __restrict__ x,
    const float* __restrict__ W_enc,
    const float* __restrict__ b_enc,
    const float* __restrict__ gamma,
    const float* __restrict__ beta,
    const float* __restrict__ run_mean,
    const float* __restrict__ run_var,
    const int* __restrict__ meta,
    float* __restrict__ concat_out,
    __hip_bfloat16* __restrict__ concat_bf, int use_bf,
    int total, int max_in, int max_out, int concat_dim) {
  int r = blockIdx.x;
  int b0 = blockIdx.y * 256;
  int in_off  = meta[r];
  int size    = meta[NROIS + r];
  int out_off = meta[2 * NROIS + r];
  int red     = meta[3 * NROIS + r];
  int ntiles  = (red + 15) >> 4;           // 1..4, block-uniform

  int t = threadIdx.x;
  int w = t >> 6, l = t & 63, lq = l >> 4, lm = l & 15;
  int rowbase = b0 + 64 * w;               // wave owns 64 batch rows

  // A fragment pointers: lane lm -> row, lane quad lq -> k-chunk of 8
  const float* xp[4];
  #pragma unroll
  for (int i = 0; i < 4; i++)
    xp[i] = x + (long)(rowbase + i * 16 + lm) * total + in_off + lq * 8;
  // B fragment pointers (W rows, clamped to valid range; garbage cols masked in epilogue)
  const float* wp[4];
  #pragma unroll
  for (int nb = 0; nb < 4; nb++) {
    int wr = nb * 16 + lm; if (wr >= red) wr = red - 1;
    wp[nb] = W_enc + ((long)r * max_out + wr) * max_in + lq * 8;
  }

  f32x4 acc[4][4];
  #pragma unroll
  for (int i = 0; i < 4; i++)
    #pragma unroll
    for (int nb = 0; nb < 4; nb++) acc[i][nb] = (f32x4){0.f, 0.f, 0.f, 0.f};

  int kfull = size & ~31;
  for (int kb = 0; kb < kfull; kb += 32) {
    bf16x8 af[4];
    #pragma unroll
    for (int i = 0; i < 4; i++) af[i] = cvt8(xp[i] + kb);
    for (int nb = 0; nb < ntiles; nb++) {  // uniform trip count
      bf16x8 bfr = cvt8(wp[nb] + kb);
      #pragma unroll
      for (int i = 0; i < 4; i++)
        acc[i][nb] = __builtin_amdgcn_mfma_f32_16x16x32_bf16(af[i], bfr, acc[i][nb], 0, 0, 0);
    }
  }
  if (kfull < size) {                      // guarded tail (one step)
    const __hip_bfloat16 bz = __float2bfloat16(0.f);
    bf16x8 af[4];
    #pragma unroll
    for (int i = 0; i < 4; i++) {
      union { bf16x8 v; __hip_bfloat16 h[8]; } u;
      #pragma unroll
      for (int e = 0; e < 8; e++) {
        int k = kfull + lq * 8 + e;
        u.h[e] = (k < size) ? __float2bfloat16(xp[i][kfull + e]) : bz;
      }
      af[i] = u.v;
    }
    for (int nb = 0; nb < ntiles; nb++) {
      union { bf16x8 v; __hip_bfloat16 h[8]; } ub;
      #pragma unroll
      for (int e = 0; e < 8; e++) {
        int k = kfull + lq * 8 + e;
        ub.h[e] = (k < size) ? __float2bfloat16(wp[nb][kfull + e]) : bz;
      }
      #pragma unroll
      for (int i = 0; i < 4; i++)
        acc[i][nb] = __builtin_amdgcn_mfma_f32_16x16x32_bf16(af[i], ub.v, acc[i][nb], 0, 0, 0);
    }
  }

  long base = (long)r * max_out;
  for (int nb = 0; nb < ntiles; nb++) {
    int oc = nb * 16 + lm;                 // C/D col = lane&15
    if (oc < red) {
      float sc  = gamma[base + oc] * rsqrtf(run_var[base + oc] + EPSV);
      float off = beta[base + oc] + sc * (b_enc[base + oc] - run_mean[base + oc]);
      #pragma unroll
      for (int i = 0; i < 4; i++) {
        #pragma unroll
        for (int j = 0; j < 4; j++) {      // C/D row = lq*4 + j
          int br = rowbase + i * 16 + lq * 4 + j;
          float y = sc * acc[i][nb][j] + off;
          y = (y > 0.f) ? y : SLOPEV * y;
          long o = (long)br * concat_dim + out_off + oc;
          concat_out[o] = y;
          if (use_bf) concat_bf[o] = __float2bfloat16(y);
        }
      }
    }
  }
}

// ---------------- reg GEMM: direct-fragment MFMA, split-K atomics into seeded reg_out ----------------
template <bool BF16SRC>
__global__ __launch_bounds__(256) void reg_kernel(
    const void* __restrict__ concat_src,
    const float* __restrict__ W_reg,
    float* __restrict__ reg_out,
    int concat_dim, int span) {
  int j0 = blockIdx.x * 64;
  int b0 = blockIdx.y * 256;
  int kstart = blockIdx.z * span;
  int kend = min(kstart + span, concat_dim);
  if (kstart >= kend) return;              // uniform exit
  int ntiles = min(4, (NREG - j0 + 15) >> 4);

  int t = threadIdx.x;
  int w = t >> 6, l = t & 63, lq = l >> 4, lm = l & 15;
  int rowbase = b0 + 64 * w;

  const __hip_bfloat16* ab[4];
  const float* af32[4];
  #pragma unroll
  for (int i = 0; i < 4; i++) {
    long ro = (long)(rowbase + i * 16 + lm) * concat_dim + lq * 8;
    ab[i]   = (const __hip_bfloat16*)concat_src + ro;
    af32[i] = (const float*)concat_src + ro;
  }
  const float* wp[4];
  #pragma unroll
  for (int nb = 0; nb < 4; nb++) {
    int jr = j0 + nb * 16 + lm; if (jr >= NREG) jr = NREG - 1;
    wp[nb] = W_reg + (long)jr * concat_dim + lq * 8;
  }

  f32x4 acc[4][4];
  #pragma unroll
  for (int i = 0; i < 4; i++)
    #pragma unroll
    for (int nb = 0; nb < 4; nb++) acc[i][nb] = (f32x4){0.f, 0.f, 0.f, 0.f};

  int kfull = kstart + ((kend - kstart) & ~31);
  for (int kb = kstart; kb < kfull; kb += 32) {
    bf16x8 af[4];
    #pragma unroll
    for (int i = 0; i < 4; i++)
      af[i] = BF16SRC ? *(const bf16x8*)(ab[i] + kb) : cvt8(af32[i] + kb);
    for (int nb = 0; nb < ntiles; nb++) {
      bf16x8 bfr = cvt8(wp[nb] + kb);
      #pragma unroll
      for (int i = 0; i < 4; i++)
        acc[i][nb] = __builtin_amdgcn_mfma_f32_16x16x32_bf16(af[i], bfr, acc[i][nb], 0, 0, 0);
    }
  }
  if (kfull < kend) {
    const __hip_bfloat16 bz = __float2bfloat16(0.f);
    bf16x8 af[4];
    #pragma unroll
    for (int i = 0; i < 4; i++) {
      union { bf16x8 v; __hip_bfloat16 h[8]; } u;
      #pragma unroll
      for (int e = 0; e < 8; e++) {
        int k = kfull + lq * 8 + e;
        u.h[e] = (k < kend) ? (BF16SRC ? ab[i][kfull + e] : __float2bfloat16(af32[i][kfull + e])) : bz;
      }
      af[i] = u.v;
    }
    for (int nb = 0; nb < ntiles; nb++) {
      union { bf16x8 v; __hip_bfloat16 h[8]; } ub;
      #pragma unroll
      for (int e = 0; e < 8; e++) {
        int k = kfull + lq * 8 + e;
        ub.h[e] = (k < kend) ? __float2bfloat16(wp[nb][kfull + e]) : bz;
      }
      #pragma unroll
      for (int i = 0; i < 4; i++)
        acc[i][nb] = __builtin_amdgcn_mfma_f32_16x16x32_bf16(af[i], ub.v, acc[i][nb], 0, 0, 0);
    }
  }

  for (int nb = 0; nb < ntiles; nb++) {
    int j = j0 + nb * 16 + lm;
    if (j < NREG) {
      #pragma unroll
      for (int i = 0; i < 4; i++) {
        #pragma unroll
        for (int jj = 0; jj < 4; jj++) {
          int br = rowbase + i * 16 + lq * 4 + jj;
          atomicAdd(&reg_out[(long)br * NREG + j], acc[i][nb][jj]);
        }
      }
    }
  }
}

// ---------------- cls: read reg_out, 180-wide GEMV (float4), softmax ----------------
__global__ __launch_bounds__(192) void cls_kernel(
    const float* __restrict__ reg_out,
    const float* __restrict__ W_cls,
    const float* __restrict__ b_cls,
    float* __restrict__ cls_out) {
  int b = blockIdx.x;
  int t = threadIdx.x;
  __shared__ __align__(16) float rrow[NREG];
  __shared__ float lm[3];
  for (int iB = t; iB < NREG; iB += 192) rrow[iB] = reg_out[(long)b * NREG + iB];
  __syncthreads();
  float s = 0.f;
  if (t < NCLS) {
    s = b_cls[t];
    const float4* wr  = (const float4*)(W_cls + (long)t * NREG);
    const float4* rr4 = (const float4*)rrow;
    #pragma unroll 5
    for (int i = 0; i < NREG / 4; ++i) {
      float4 wv = wr[i], rv = rr4[i];
      s += wv.x * rv.x + wv.y * rv.y + wv.z * rv.z + wv.w * rv.w;
    }
  }
  float v = (t < NCLS) ? s : -3.4e38f;
  #pragma unroll
  for (int o = 32; o > 0; o >>= 1) v = fmaxf(v, __shfl_xor(v, o, 64));
  if ((t & 63) == 0) lm[t >> 6] = v;
  __syncthreads();
  float bmax = fmaxf(fmaxf(lm[0], lm[1]), lm[2]);
  __syncthreads();
  float e = (t < NCLS) ? __expf(s - bmax) : 0.f;
  float ss = e;
  #pragma unroll
  for (int o = 32; o > 0; o >>= 1) ss += __shfl_xor(ss, o, 64);
  if ((t & 63) == 0) lm[t >> 6] = ss;
  __syncthreads();
  float bsum = lm[0] + lm[1] + lm[2];
  if (t < NCLS) cls_out[(long)b * NCLS + t] = e / bsum;
}

extern "C" void kernel_launch(void* const* d_in, const int* in_sizes, int n_in,
                              void* d_out, int out_size, void* d_ws, size_t ws_size,
                              hipStream_t stream) {
  const float* x     = (const float*)d_in[0];
  const float* W_enc = (const float*)d_in[1];
  const float* b_enc = (const float*)d_in[2];
  const float* gam   = (const float*)d_in[3];
  const float* bet   = (const float*)d_in[4];
  const float* rmean = (const float*)d_in[5];
  const float* rvar  = (const float*)d_in[6];
  const float* W_reg = (const float*)d_in[7];
  const float* b_reg = (const float*)d_in[8];
  const float* W_cls = (const float*)d_in[9];
  const float* b_cls = (const float*)d_in[10];
  const int* idx = (const int*)d_in[11];
  const int* src = (const int*)d_in[12];

  int total      = in_sizes[0] / BATCH;
  int max_out    = in_sizes[2] / NROIS;
  int max_in     = in_sizes[11] / NROIS;
  int concat_dim = in_sizes[12];

  int* meta = (int*)d_ws;  // 4*NROIS ints
  size_t bf_off  = 8192;
  size_t bf_need = bf_off + (size_t)BATCH * concat_dim * sizeof(__hip_bfloat16);
  int use_bf = (ws_size >= bf_need) ? 1 : 0;
  __hip_bfloat16* concat_bf = (__hip_bfloat16*)((char*)d_ws + bf_off);

  float* out_concat = (float*)d_out;
  float* out_reg = out_concat + (long)BATCH * concat_dim;
  float* out_cls = out_reg + (long)BATCH * NREG;

  meta_kernel<<<dim3((NROIS + 255) / 256), 256, 0, stream>>>(idx, src, meta, max_in, max_out, total, concat_dim);
  init_reg_kernel<<<dim3((BATCH * NREG + 255) / 256), 256, 0, stream>>>(b_reg, out_reg);
  enc_kernel<<<dim3(NROIS, BATCH / 256), 256, 0, stream>>>(x, W_enc, b_enc, gam, bet, rmean, rvar,
                                                           meta, out_concat, concat_bf, use_bf,
                                                           total, max_in, max_out, concat_dim);
  const int SPLIT = 32;
  int span = ((concat_dim + SPLIT * 32 - 1) / (SPLIT * 32)) * 32;
  dim3 rgrid((NREG + 63) / 64, BATCH / 256, SPLIT);
  if (use_bf)
    reg_kernel<true><<<rgrid, 256, 0, stream>>>(concat_bf, W_reg, out_reg, concat_dim, span);
  else
    reg_kernel<false><<<rgrid, 256, 0, stream>>>(out_concat, W_reg, out_reg, concat_dim, span);
  cls_kernel<<<BATCH, 192, 0, stream>>>(out_reg, W_cls, b_cls, out_cls);
}

// Round 5
// 471.796 us; speedup vs baseline: 1.7262x; 1.7262x over previous
//
#include <hip/hip_runtime.h>
#include <hip/hip_bf16.h>

#define NROIS 333
#define BATCH 512
#define NREG 300
#define NCLS 180
#define EPSV 1e-5f
#define SLOPEV 0.3f

typedef __attribute__((ext_vector_type(8))) short bf16x8;
typedef __attribute__((ext_vector_type(4))) float f32x4;

static __device__ __forceinline__ bf16x8 pack8(const float v[8]) {
  union { bf16x8 o; __hip_bfloat16 h[8]; } u;
  #pragma unroll
  for (int e = 0; e < 8; e++) u.h[e] = __float2bfloat16(v[e]);
  return u.o;
}

// ---------------- metadata: {in_off, size, out_off, reduced} via binary search ----------------
__global__ void meta_kernel(const int* __restrict__ idx, const int* __restrict__ src,
                            int* __restrict__ meta, int max_in, int max_out,
                            int total, int concat_dim) {
  int r = blockIdx.x * blockDim.x + threadIdx.x;
  if (r >= NROIS) return;
  const int* row = idx + (long)r * max_in;
  int in_off = row[0];
  int lo = 0, hi = max_in;
  while (lo < hi) { int mid = (lo + hi) >> 1; if (row[mid] < total) lo = mid + 1; else hi = mid; }
  int size = lo;
  int t1 = r * max_out;
  lo = 0; hi = concat_dim;
  while (lo < hi) { int mid = (lo + hi) >> 1; if (src[mid] < t1) lo = mid + 1; else hi = mid; }
  int out_off = lo;
  int t2 = t1 + max_out;
  hi = concat_dim;
  while (lo < hi) { int mid = (lo + hi) >> 1; if (src[mid] < t2) lo = mid + 1; else hi = mid; }
  meta[r] = in_off;
  meta[NROIS + r] = size;
  meta[2 * NROIS + r] = out_off;
  meta[3 * NROIS + r] = lo - out_off;
}

__global__ void init_reg_kernel(const float* __restrict__ b_reg, float* __restrict__ reg_out) {
  int i = blockIdx.x * blockDim.x + threadIdx.x;
  if (i < BATCH * NREG) reg_out[i] = b_reg[i % NREG];
}

// ---------------- encoder: LDS dbuf-pipelined MFMA + BN + leaky ----------------
// M=128 rows/block, K-step 64, 1 barrier/step. LDS rows = 64 bf16 (8 b128 chunks),
// chunk XOR-swizzled by (row&7) so writes AND fragment reads sit at the b128 bank floor.
__global__ __launch_bounds__(256) void enc_kernel(
    const float* __restrict__ x,
    const float* __restrict__ W_enc,
    const float* __restrict__ b_enc,
    const float* __restrict__ gamma,
    const float* __restrict__ beta,
    const float* __restrict__ run_mean,
    const float* __restrict__ run_var,
    const int* __restrict__ meta,
    float* __restrict__ concat_out,
    int total, int max_in, int max_out, int concat_dim) {
  int r = blockIdx.x;
  int b0 = blockIdx.y * 128;
  int in_off  = meta[r];
  int size    = meta[NROIS + r];
  int out_off = meta[2 * NROIS + r];
  int red     = meta[3 * NROIS + r];
  int ntiles  = (red + 15) >> 4;          // 1..4, block-uniform

  __shared__ __hip_bfloat16 xs[2][128 * 64];
  __shared__ __hip_bfloat16 wsh[2][64 * 64];

  int t = threadIdx.x;
  // staging coords: thread covers chunk chk (of 8 bf16) in rows rbase+32s
  int rbase = t >> 3, chk = t & 7;
  const float* xg0 = x + (long)(b0 + rbase) * total + in_off;
  long xstride = (long)32 * total;
  const float* wg0 = W_enc + ((long)r * max_out + rbase) * max_in;
  long wstride = (long)32 * max_in;

  // compute coords: wave w owns rows 32w..32w+31
  int w = t >> 6, l = t & 63, lq = l >> 4, lm = l & 15;

  f32x4 acc[2][4];
  #pragma unroll
  for (int i = 0; i < 2; i++)
    #pragma unroll
    for (int nb = 0; nb < 4; nb++) acc[i][nb] = (f32x4){0.f, 0.f, 0.f, 0.f};

  int nsteps = (size + 63) >> 6;
  float xr[4][8], wr[2][8];

  // ---- load slab kb into registers (guarded) ----
  auto load_regs = [&](int kb) {
    int k0 = kb + chk * 8;
    if (k0 + 8 <= size) {
      #pragma unroll
      for (int s = 0; s < 4; s++) {
        const float* p = xg0 + (long)s * xstride + k0;
        float4 a = *(const float4*)p, b = *(const float4*)(p + 4);
        xr[s][0]=a.x; xr[s][1]=a.y; xr[s][2]=a.z; xr[s][3]=a.w;
        xr[s][4]=b.x; xr[s][5]=b.y; xr[s][6]=b.z; xr[s][7]=b.w;
      }
      #pragma unroll
      for (int s = 0; s < 2; s++) {
        if (rbase + 32 * s < red) {
          const float* p = wg0 + (long)s * wstride + k0;
          float4 a = *(const float4*)p, b = *(const float4*)(p + 4);
          wr[s][0]=a.x; wr[s][1]=a.y; wr[s][2]=a.z; wr[s][3]=a.w;
          wr[s][4]=b.x; wr[s][5]=b.y; wr[s][6]=b.z; wr[s][7]=b.w;
        } else {
          #pragma unroll
          for (int e = 0; e < 8; e++) wr[s][e] = 0.f;
        }
      }
    } else {
      #pragma unroll
      for (int s = 0; s < 4; s++)
        #pragma unroll
        for (int e = 0; e < 8; e++)
          xr[s][e] = (k0 + e < size) ? xg0[(long)s * xstride + k0 + e] : 0.f;
      #pragma unroll
      for (int s = 0; s < 2; s++) {
        bool rv = rbase + 32 * s < red;
        #pragma unroll
        for (int e = 0; e < 8; e++)
          wr[s][e] = (rv && k0 + e < size) ? wg0[(long)s * wstride + k0 + e] : 0.f;
      }
    }
  };
  auto write_lds = [&](int buf) {
    #pragma unroll
    for (int s = 0; s < 4; s++) {
      int row = rbase + 32 * s, cs = chk ^ (row & 7);
      *(bf16x8*)&xs[buf][(row * 8 + cs) * 8] = pack8(xr[s]);
    }
    #pragma unroll
    for (int s = 0; s < 2; s++) {
      int row = rbase + 32 * s, cs = chk ^ (row & 7);
      *(bf16x8*)&wsh[buf][(row * 8 + cs) * 8] = pack8(wr[s]);
    }
  };

  load_regs(0);
  write_lds(0);
  __syncthreads();

  for (int s = 0; s < nsteps; s++) {
    int buf = s & 1;
    bool more = (s + 1 < nsteps);
    if (more) load_regs((s + 1) * 64);
    #pragma unroll
    for (int kk = 0; kk < 2; kk++) {
      bf16x8 af[2];
      #pragma unroll
      for (int i = 0; i < 2; i++) {
        int row = 32 * w + 16 * i + lm, cs = (lq + 4 * kk) ^ (row & 7);
        af[i] = *(const bf16x8*)&xs[buf][(row * 8 + cs) * 8];
      }
      for (int nb = 0; nb < ntiles; nb++) {   // block-uniform trip count
        int row = 16 * nb + lm, cs = (lq + 4 * kk) ^ (row & 7);
        bf16x8 bfr = *(const bf16x8*)&wsh[buf][(row * 8 + cs) * 8];
        #pragma unroll
        for (int i = 0; i < 2; i++)
          acc[i][nb] = __builtin_amdgcn_mfma_f32_16x16x32_bf16(af[i], bfr, acc[i][nb], 0, 0, 0);
      }
    }
    if (more) write_lds(buf ^ 1);
    __syncthreads();
  }

  long base = (long)r * max_out;
  for (int nb = 0; nb < ntiles; nb++) {
    int oc = nb * 16 + lm;                    // C/D col = lane&15
    if (oc < red) {
      float sc  = gamma[base + oc] * rsqrtf(run_var[base + oc] + EPSV);
      float off = beta[base + oc] + sc * (b_enc[base + oc] - run_mean[base + oc]);
      #pragma unroll
      for (int i = 0; i < 2; i++) {
        #pragma unroll
        for (int j = 0; j < 4; j++) {         // C/D row = lq*4 + j
          int br = b0 + 32 * w + 16 * i + lq * 4 + j;
          float y = sc * acc[i][nb][j] + off;
          y = (y > 0.f) ? y : SLOPEV * y;
          concat_out[(long)br * concat_dim + out_off + oc] = y;
        }
      }
    }
  }
}

// ---------------- reg GEMM: same pipelined skeleton, split-K atomics into seeded reg_out ----------------
__global__ __launch_bounds__(256) void reg_kernel(
    const float* __restrict__ concat,
    const float* __restrict__ W_reg,
    float* __restrict__ reg_out,
    int concat_dim, int span) {
  int j0 = blockIdx.x * 64;
  int b0 = blockIdx.y * 128;
  int kstart = blockIdx.z * span;
  int kend = min(kstart + span, concat_dim);
  if (kstart >= kend) return;               // uniform exit
  int ntiles = min(4, (NREG - j0 + 15) >> 4);
  int klen = kend - kstart;

  __shared__ __hip_bfloat16 as_[2][128 * 64];
  __shared__ __hip_bfloat16 bs_[2][64 * 64];

  int t = threadIdx.x;
  int rbase = t >> 3, chk = t & 7;
  const float* ag0 = concat + (long)(b0 + rbase) * concat_dim + kstart;
  long astride = (long)32 * concat_dim;
  const float* bg0 = W_reg + (long)(j0 + rbase) * concat_dim + kstart;
  long bstride = (long)32 * concat_dim;

  int w = t >> 6, l = t & 63, lq = l >> 4, lm = l & 15;

  f32x4 acc[2][4];
  #pragma unroll
  for (int i = 0; i < 2; i++)
    #pragma unroll
    for (int nb = 0; nb < 4; nb++) acc[i][nb] = (f32x4){0.f, 0.f, 0.f, 0.f};

  int nsteps = (klen + 63) >> 6;
  float ar[4][8], br[2][8];

  auto load_regs = [&](int kb) {
    int k0 = kb + chk * 8;
    if (k0 + 8 <= klen) {
      #pragma unroll
      for (int s = 0; s < 4; s++) {
        const float* p = ag0 + (long)s * astride + k0;
        float4 a = *(const float4*)p, b = *(const float4*)(p + 4);
        ar[s][0]=a.x; ar[s][1]=a.y; ar[s][2]=a.z; ar[s][3]=a.w;
        ar[s][4]=b.x; ar[s][5]=b.y; ar[s][6]=b.z; ar[s][7]=b.w;
      }
      #pragma unroll
      for (int s = 0; s < 2; s++) {
        if (j0 + rbase + 32 * s < NREG) {
          const float* p = bg0 + (long)s * bstride + k0;
          float4 a = *(const float4*)p, b = *(const float4*)(p + 4);
          br[s][0]=a.x; br[s][1]=a.y; br[s][2]=a.z; br[s][3]=a.w;
          br[s][4]=b.x; br[s][5]=b.y; br[s][6]=b.z; br[s][7]=b.w;
        } else {
          #pragma unroll
          for (int e = 0; e < 8; e++) br[s][e] = 0.f;
        }
      }
    } else {
      #pragma unroll
      for (int s = 0; s < 4; s++)
        #pragma unroll
        for (int e = 0; e < 8; e++)
          ar[s][e] = (k0 + e < klen) ? ag0[(long)s * astride + k0 + e] : 0.f;
      #pragma unroll
      for (int s = 0; s < 2; s++) {
        bool rv = j0 + rbase + 32 * s < NREG;
        #pragma unroll
        for (int e = 0; e < 8; e++)
          br[s][e] = (rv && k0 + e < klen) ? bg0[(long)s * bstride + k0 + e] : 0.f;
      }
    }
  };
  auto write_lds = [&](int buf) {
    #pragma unroll
    for (int s = 0; s < 4; s++) {
      int row = rbase + 32 * s, cs = chk ^ (row & 7);
      *(bf16x8*)&as_[buf][(row * 8 + cs) * 8] = pack8(ar[s]);
    }
    #pragma unroll
    for (int s = 0; s < 2; s++) {
      int row = rbase + 32 * s, cs = chk ^ (row & 7);
      *(bf16x8*)&bs_[buf][(row * 8 + cs) * 8] = pack8(br[s]);
    }
  };

  load_regs(0);
  write_lds(0);
  __syncthreads();

  for (int s = 0; s < nsteps; s++) {
    int buf = s & 1;
    bool more = (s + 1 < nsteps);
    if (more) load_regs((s + 1) * 64);
    #pragma unroll
    for (int kk = 0; kk < 2; kk++) {
      bf16x8 af[2];
      #pragma unroll
      for (int i = 0; i < 2; i++) {
        int row = 32 * w + 16 * i + lm, cs = (lq + 4 * kk) ^ (row & 7);
        af[i] = *(const bf16x8*)&as_[buf][(row * 8 + cs) * 8];
      }
      for (int nb = 0; nb < ntiles; nb++) {
        int row = 16 * nb + lm, cs = (lq + 4 * kk) ^ (row & 7);
        bf16x8 bfr = *(const bf16x8*)&bs_[buf][(row * 8 + cs) * 8];
        #pragma unroll
        for (int i = 0; i < 2; i++)
          acc[i][nb] = __builtin_amdgcn_mfma_f32_16x16x32_bf16(af[i], bfr, acc[i][nb], 0, 0, 0);
      }
    }
    if (more) write_lds(buf ^ 1);
    __syncthreads();
  }

  for (int nb = 0; nb < ntiles; nb++) {
    int j = j0 + nb * 16 + lm;
    if (j < NREG) {
      #pragma unroll
      for (int i = 0; i < 2; i++)
        #pragma unroll
        for (int jj = 0; jj < 4; jj++) {
          int br2 = b0 + 32 * w + 16 * i + lq * 4 + jj;
          atomicAdd(&reg_out[(long)br2 * NREG + j], acc[i][nb][jj]);
        }
    }
  }
}

// ---------------- cls: read reg_out, 180-wide GEMV (float4), softmax ----------------
__global__ __launch_bounds__(192) void cls_kernel(
    const float* __restrict__ reg_out,
    const float* __restrict__ W_cls,
    const float* __restrict__ b_cls,
    float* __restrict__ cls_out) {
  int b = blockIdx.x;
  int t = threadIdx.x;
  __shared__ __align__(16) float rrow[NREG];
  __shared__ float lm[3];
  for (int iB = t; iB < NREG; iB += 192) rrow[iB] = reg_out[(long)b * NREG + iB];
  __syncthreads();
  float s = 0.f;
  if (t < NCLS) {
    s = b_cls[t];
    const float4* wr  = (const float4*)(W_cls + (long)t * NREG);
    const float4* rr4 = (const float4*)rrow;
    #pragma unroll 5
    for (int i = 0; i < NREG / 4; ++i) {
      float4 wv = wr[i], rv = rr4[i];
      s += wv.x * rv.x + wv.y * rv.y + wv.z * rv.z + wv.w * rv.w;
    }
  }
  float v = (t < NCLS) ? s : -3.4e38f;
  #pragma unroll
  for (int o = 32; o > 0; o >>= 1) v = fmaxf(v, __shfl_xor(v, o, 64));
  if ((t & 63) == 0) lm[t >> 6] = v;
  __syncthreads();
  float bmax = fmaxf(fmaxf(lm[0], lm[1]), lm[2]);
  __syncthreads();
  float e = (t < NCLS) ? __expf(s - bmax) : 0.f;
  float ss = e;
  #pragma unroll
  for (int o = 32; o > 0; o >>= 1) ss += __shfl_xor(ss, o, 64);
  if ((t & 63) == 0) lm[t >> 6] = ss;
  __syncthreads();
  float bsum = lm[0] + lm[1] + lm[2];
  if (t < NCLS) cls_out[(long)b * NCLS + t] = e / bsum;
}

extern "C" void kernel_launch(void* const* d_in, const int* in_sizes, int n_in,
                              void* d_out, int out_size, void* d_ws, size_t ws_size,
                              hipStream_t stream) {
  const float* x     = (const float*)d_in[0];
  const float* W_enc = (const float*)d_in[1];
  const float* b_enc = (const float*)d_in[2];
  const float* gam   = (const float*)d_in[3];
  const float* bet   = (const float*)d_in[4];
  const float* rmean = (const float*)d_in[5];
  const float* rvar  = (const float*)d_in[6];
  const float* W_reg = (const float*)d_in[7];
  const float* b_reg = (const float*)d_in[8];
  const float* W_cls = (const float*)d_in[9];
  const float* b_cls = (const float*)d_in[10];
  const int* idx = (const int*)d_in[11];
  const int* src = (const int*)d_in[12];

  int total      = in_sizes[0] / BATCH;
  int max_out    = in_sizes[2] / NROIS;
  int max_in     = in_sizes[11] / NROIS;
  int concat_dim = in_sizes[12];

  int* meta = (int*)d_ws;

  float* out_concat = (float*)d_out;
  float* out_reg = out_concat + (long)BATCH * concat_dim;
  float* out_cls = out_reg + (long)BATCH * NREG;

  meta_kernel<<<dim3((NROIS + 255) / 256), 256, 0, stream>>>(idx, src, meta, max_in, max_out, total, concat_dim);
  init_reg_kernel<<<dim3((BATCH * NREG + 255) / 256), 256, 0, stream>>>(b_reg, out_reg);
  enc_kernel<<<dim3(NROIS, BATCH / 128), 256, 0, stream>>>(x, W_enc, b_enc, gam, bet, rmean, rvar,
                                                           meta, out_concat, total, max_in, max_out, concat_dim);
  const int SPAN = 448;                      // multiple of 64
  int nsplit = (concat_dim + SPAN - 1) / SPAN;
  reg_kernel<<<dim3((NREG + 63) / 64, BATCH / 128, nsplit), 256, 0, stream>>>(out_concat, W_reg, out_reg, concat_dim, SPAN);
  cls_kernel<<<BATCH, 192, 0, stream>>>(out_reg, W_cls, b_cls, out_cls);
}